// Round 7
// baseline (310.360 us; speedup 1.0000x reference)
//
#include <hip/hip_runtime.h>
#include <hip/hip_cooperative_groups.h>
#include <cmath>

#define D_ 128
#define H_ 256
#define W4 64                         // 4-elem groups per row (256 wide)
#define PS (H_*W4)                    // plane stride in groups (16384)
#define NTOT (2*128*256*256)
#define GBLK 2048                     // b(2)*d(128)*h-eighth(8)
#define ROWS 8                        // rows per thread
#define TSTART 6                      // fallback path: first coop-tail iteration
#define STOPF 1e-4f

typedef _Float16 h4 __attribute__((ext_vector_type(4)));
typedef _Float16 h2v __attribute__((ext_vector_type(2)));

__device__ __forceinline__ float lk(float x){ return x >= 0.f ? x : 0.01f*x; }
__device__ __forceinline__ float4 mn4(float4 a, float4 b){
    return make_float4(fminf(a.x,b.x),fminf(a.y,b.y),fminf(a.z,b.z),fminf(a.w,b.w)); }
__device__ __forceinline__ float4 ld4(const float4* p){ return *p; }
__device__ __forceinline__ float4 ld4(const h4* p){
    h4 v = *p; return make_float4((float)v.x,(float)v.y,(float)v.z,(float)v.w); }
__device__ __forceinline__ void st4(h4* p, float4 v){
    h4 r; r.x=(_Float16)v.x; r.y=(_Float16)v.y; r.z=(_Float16)v.z; r.w=(_Float16)v.w; *p = r; }
__device__ __forceinline__ float4 h4tof4(h4 v){
    return make_float4((float)v.x,(float)v.y,(float)v.z,(float)v.w); }
__device__ __forceinline__ h4 f4toh4(float4 v){
    h4 r; r.x=(_Float16)v.x; r.y=(_Float16)v.y; r.z=(_Float16)v.z; r.w=(_Float16)v.w; return r; }

// ---- packed fp16 helpers: v_pk_min/max_f16 (selection ops -> bit-exact) ----
#define PINF 0x7C007C00u
#define NINF 0xFC00FC00u
__device__ __forceinline__ uint32_t pmin(uint32_t a, uint32_t b){
    h2v r = __builtin_elementwise_min(__builtin_bit_cast(h2v,a), __builtin_bit_cast(h2v,b));
    return __builtin_bit_cast(uint32_t, r); }
__device__ __forceinline__ uint32_t pmax(uint32_t a, uint32_t b){
    h2v r = __builtin_elementwise_max(__builtin_bit_cast(h2v,a), __builtin_bit_cast(h2v,b));
    return __builtin_bit_cast(uint32_t, r); }
__device__ __forceinline__ uint2 pmin2(uint2 a, uint2 b){
    return make_uint2(pmin(a.x,b.x), pmin(a.y,b.y)); }
__device__ __forceinline__ uint2 pmax2(uint2 a, uint2 b){
    return make_uint2(pmax(a.x,b.x), pmax(a.y,b.y)); }
__device__ __forceinline__ float4 cvt4(uint32_t w01, uint32_t w23){
    h2v a = __builtin_bit_cast(h2v, w01);
    h2v b = __builtin_bit_cast(h2v, w23);
    return make_float4((float)a.x, (float)a.y, (float)b.x, (float)b.y); }
__device__ __forceinline__ uint2 pk4(float4 v){      // f32x4 -> packed fp16 (RTN)
    return __builtin_bit_cast(uint2, f4toh4(v)); }

// horizontal (w-axis) window min/max: input = d/h-merged packed pair for 4 elems
__device__ __forceinline__ uint2 hmin2(uint2 v, int lane){
    uint32_t pw = __shfl_up(v.y,1);   if (lane == 0)  pw = PINF;
    uint32_t nw = __shfl_down(v.x,1); if (lane == 63) nw = PINF;
    uint32_t l01 = (pw  >> 16) | (v.x << 16);
    uint32_t l23 = (v.x >> 16) | (v.y << 16);
    uint32_t r23 = (v.y >> 16) | (nw  << 16);
    return make_uint2(pmin(pmin(l01,v.x),l23), pmin(pmin(l23,v.y),r23));
}
__device__ __forceinline__ uint2 hmax2(uint2 v, int lane){
    uint32_t pw = __shfl_up(v.y,1);   if (lane == 0)  pw = NINF;
    uint32_t nw = __shfl_down(v.x,1); if (lane == 63) nw = NINF;
    uint32_t l01 = (pw  >> 16) | (v.x << 16);
    uint32_t l23 = (v.x >> 16) | (v.y << 16);
    uint32_t r23 = (v.y >> 16) | (nw  << 16);
    return make_uint2(pmax(pmax(l01,v.x),l23), pmax(pmax(l23,v.y),r23));
}

// geometry: block bi covers (b, d, h-eighth); wave owns ROWS rows.
// h-eighth in LOW 3 bits -> d-neighbor blocks (share X planes) on same XCD.
struct Geo { int lane, h0; size_t pbase; bool pm, pp; };
__device__ __forceinline__ Geo mkgeo(int tid, int bi){
    Geo g;
    g.lane = tid & 63;
    int wv = tid >> 6;
    int q = bi & 7, d = (bi >> 3) & 127, b = bi >> 10;
    g.h0 = q*32 + wv*ROWS;
    g.pbase = ((size_t)(b*128 + d))*PS + (size_t)g.lane;
    g.pm = (d > 0); g.pp = (d < 127);
    return g;
}

// ===================== FUSED PATH ===========================================
// init_k: R0 = erode(img0), R1 = erode(R0), S = leaky(img0 - dilate(R0)).
// fp16 rounding is monotone => fp16(min_f32(..)) == min_fp16(fp16(..)):
// round img0 once, morphology all-packed-fp16 -> bit-identical to p0+p1.
__global__ __launch_bounds__(256) void init_k(const float* __restrict__ img0,
                                              h4* __restrict__ R0,
                                              h4* __restrict__ R1,
                                              h4* __restrict__ Sb,
                                              int* __restrict__ frozen){
    if (blockIdx.x == 0 && threadIdx.x == 0) *frozen = 0;
    int tid = threadIdx.x, lane = tid & 63, wv = tid >> 6;
    int bi = blockIdx.x;
    int q = bi & 7, d = (bi >> 3) & 127, b = bi >> 10;
    int h0 = q*32 + wv*8;                      // multiple of 8 -> ring idx compile-time
    size_t pbase = ((size_t)(b*128 + d))*PS + (size_t)lane;
    bool dm1 = d >= 1, dm2 = d >= 2, dp1 = d <= 126, dp2 = d <= 125;
    const float4* Xc = (const float4*)img0 + pbase;
    uint2* E1w = (uint2*)R0 + pbase;
    uint2* E2w = (uint2*)R1 + pbase;
    h4*    Sw  = Sb + pbase;

    float4 rawC[4];
    uint2 mnA[4], mnB[4], mnC[4], mnE[4], mxE[4];

    auto ldmg = [&](int h, int sl){
        if (h >= 0 && h < H_){
            const float4* p = Xc + h*W4;
            float4 c4 = p[0]; rawC[sl] = c4;
            uint2 c = pk4(c4);
            uint2 xm1, xm2, xp1, xp2;
            if (dm1) xm1 = pk4(p[-(int)PS]);
            if (dm2) xm2 = pk4(p[-2*(int)PS]);
            if (dp1) xp1 = pk4(p[(int)PS]);
            if (dp2) xp2 = pk4(p[2*(int)PS]);
            uint2 mb = c;
            if (dm1) mb = pmin2(mb, xm1);
            if (dp1) mb = pmin2(mb, xp1);
            mnB[sl] = mb;
            if (dm1){ uint2 a = pmin2(xm1, c); if (dm2) a = pmin2(a, xm2); mnA[sl] = a; }
            if (dp1){ uint2 cc = pmin2(xp1, c); if (dp2) cc = pmin2(cc, xp2); mnC[sl] = cc; }
        } else {
            mnA[sl] = make_uint2(PINF,PINF); mnB[sl] = make_uint2(PINF,PINF);
            mnC[sl] = make_uint2(PINF,PINF);
            rawC[sl] = make_float4(0,0,0,0);
        }
    };
    auto e1row = [&](int e, int s0, int s1, int s2, int se, bool wr){
        if (e >= 0 && e < H_){
            uint2 vb = pmin2(mnB[s0], pmin2(mnB[s1], mnB[s2]));
            uint2 e1b = hmin2(vb, lane);
            uint2 mn = e1b, mx = e1b;
            if (dm1){
                uint2 va = pmin2(mnA[s0], pmin2(mnA[s1], mnA[s2]));
                uint2 e1a = hmin2(va, lane);
                mn = pmin2(mn, e1a); mx = pmax2(mx, e1a);
            }
            if (dp1){
                uint2 vc = pmin2(mnC[s0], pmin2(mnC[s1], mnC[s2]));
                uint2 e1c = hmin2(vc, lane);
                mn = pmin2(mn, e1c); mx = pmax2(mx, e1c);
            }
            mnE[se] = mn; mxE[se] = mx;
            if (wr) E1w[e*W4] = e1b;
        } else { mnE[se] = make_uint2(PINF,PINF); mxE[se] = make_uint2(NINF,NINF); }
    };

    ldmg(h0-2, 2); ldmg(h0-1, 3); ldmg(h0+0, 0); ldmg(h0+1, 1);
    e1row(h0-1, 2,3,0, 3, false);
    e1row(h0+0, 3,0,1, 0, true);
#pragma unroll
    for (int rr = 0; rr < 8; ++rr){
        int r = h0 + rr;
        ldmg(r+2, (rr+2)&3);
        e1row(r+1, rr&3, (rr+1)&3, (rr+2)&3, (rr+1)&3, rr < 7);
        uint2 v2 = pmin2(mnE[(rr+3)&3], pmin2(mnE[rr&3], mnE[(rr+1)&3]));
        E2w[r*W4] = hmin2(v2, lane);
        uint2 vv = pmax2(mxE[(rr+3)&3], pmax2(mxE[rr&3], mxE[(rr+1)&3]));
        uint2 ow = hmax2(vv, lane);
        float4 o = cvt4(ow.x, ow.y);
        float4 a = rawC[rr&3];                 // img0 in f32 (exact p1 semantics)
        float4 s0;
        s0.x = lk(a.x-o.x); s0.y = lk(a.y-o.y);
        s0.z = lk(a.z-o.z); s0.w = lk(a.w-o.w);
        st4(Sw + r*W4, s0);
    }
}

// pair_k: iterations i=2p and i+1 fused. X=img_{i+2}; CE1: in C=img_{i+1},
// out E1=img_{i+3} (same buffer; same-thread row ownership + load-before-store
// makes the alias safe); E2=img_{i+4}. S updated twice with the fp16 rounding
// between (bit-identical to two dispatches); Sprev backs up S_i for freeze
// recovery. Entry gate: freeze from norm_{i-2} (-> out=1.1*Sprev) or
// norm_{i-1} (-> out=1.1*S), earliest-iteration priority.
template<bool FIRST, bool P0>
__global__ __launch_bounds__(256) void pair_k(const h4* __restrict__ Xb,
                                              h4* CE1,
                                              h4* __restrict__ E2b,
                                              h4* __restrict__ Sb,
                                              h4* __restrict__ Spb,
                                              double* __restrict__ nA,
                                              double* __restrict__ nB,
                                              const double* __restrict__ g2,
                                              const double* __restrict__ g1,
                                              int* __restrict__ frozen,
                                              float* __restrict__ outp,
                                              float lr0, float lr1){
    if (*frozen) return;
    __shared__ double s2w[4], s1w[4], smA[4], smB[4];
    int tid = threadIdx.x, lane = tid & 63, wv = tid >> 6;
    int bi = blockIdx.x;
    int q = bi & 7, d = (bi >> 3) & 127, b = bi >> 10;
    int h0 = q*32 + wv*8;
    size_t pbase = ((size_t)(b*128 + d))*PS + (size_t)lane;
    if constexpr(!P0){
        double v2 = 0.0, v1 = 0.0;
#pragma unroll
        for (int j = 0; j < GBLK/256; ++j){ v2 += g2[tid + 256*j]; v1 += g1[tid + 256*j]; }
#pragma unroll
        for (int o = 32; o; o >>= 1){ v2 += __shfl_down(v2,o); v1 += __shfl_down(v1,o); }
        if (lane == 0){ s2w[wv] = v2; s1w[wv] = v1; }
        __syncthreads();
        double t2 = s2w[0]+s2w[1]+s2w[2]+s2w[3];
        double t1 = s1w[0]+s1w[1]+s1w[2]+s1w[3];
        bool f2 = (float)(t2 / (double)NTOT) < STOPF;
        bool f1 = (float)(t1 / (double)NTOT) < STOPF;
        if (f2 || f1){
            if (tid == 0) *frozen = 1;
            const h4* Sf = (f2 ? Spb : Sb) + pbase;
            float4* O = (float4*)outp + pbase;
#pragma unroll
            for (int r = 0; r < 8; ++r){
                float4 s = h4tof4(Sf[(h0+r)*W4]);
                O[(h0+r)*W4] = make_float4(1.1f*s.x, 1.1f*s.y, 1.1f*s.z, 1.1f*s.w);
            }
            return;
        }
    }
    bool dm1 = d >= 1, dm2 = d >= 2, dp1 = d <= 126, dp2 = d <= 125;
    const uint2* Xc = (const uint2*)Xb + pbase;
    const uint2* Cr = (const uint2*)CE1 + pbase;   // aliased: no restrict
    uint2*       E1w = (uint2*)CE1 + pbase;
    uint2*       E2w = (uint2*)E2b + pbase;
    const uint2* Sr  = (const uint2*)Sb + pbase;
    uint2*       Sw  = (uint2*)Sb + pbase;
    uint2*       Spw = (uint2*)Spb + pbase;

    uint2 rawC[4], mnA[4], mnB[4], mnC[4], mxB[4], mnE[4], mxE[4];
    auto ldmg = [&](int h, int sl){
        if (h >= 0 && h < H_){
            const uint2* p = Xc + h*W4;
            uint2 c = p[0]; rawC[sl] = c;
            uint2 xm1, xm2, xp1, xp2;
            if (dm1) xm1 = p[-(int)PS];
            if (dm2) xm2 = p[-2*(int)PS];
            if (dp1) xp1 = p[(int)PS];
            if (dp2) xp2 = p[2*(int)PS];
            uint2 mb = c, xb = c;
            if (dm1){ mb = pmin2(mb, xm1); xb = pmax2(xb, xm1); }
            if (dp1){ mb = pmin2(mb, xp1); xb = pmax2(xb, xp1); }
            mnB[sl] = mb; mxB[sl] = xb;
            if (dm1){ uint2 a = pmin2(xm1, c); if (dm2) a = pmin2(a, xm2); mnA[sl] = a; }
            if (dp1){ uint2 cc = pmin2(xp1, c); if (dp2) cc = pmin2(cc, xp2); mnC[sl] = cc; }
        } else {
            mnA[sl] = make_uint2(PINF,PINF); mnB[sl] = make_uint2(PINF,PINF);
            mnC[sl] = make_uint2(PINF,PINF); mxB[sl] = make_uint2(NINF,NINF);
            rawC[sl] = make_uint2(0,0);
        }
    };
    auto e1row = [&](int e, int s0, int s1, int s2, int se, bool wr){
        if (e >= 0 && e < H_){
            uint2 vb = pmin2(mnB[s0], pmin2(mnB[s1], mnB[s2]));
            uint2 e1b = hmin2(vb, lane);
            uint2 mn = e1b, mx = e1b;
            if (dm1){
                uint2 va = pmin2(mnA[s0], pmin2(mnA[s1], mnA[s2]));
                uint2 e1a = hmin2(va, lane);
                mn = pmin2(mn, e1a); mx = pmax2(mx, e1a);
            }
            if (dp1){
                uint2 vc = pmin2(mnC[s0], pmin2(mnC[s1], mnC[s2]));
                uint2 e1c = hmin2(vc, lane);
                mn = pmin2(mn, e1c); mx = pmax2(mx, e1c);
            }
            mnE[se] = mn; mxE[se] = mx;
            if (wr) E1w[e*W4] = e1b;
        } else { mnE[se] = make_uint2(PINF,PINF); mxE[se] = make_uint2(NINF,NINF); }
    };

    ldmg(h0-2, 2); ldmg(h0-1, 3); ldmg(h0+0, 0); ldmg(h0+1, 1);
    uint2 cw_cur = Cr[h0*W4];                  // load C[h0] BEFORE E1B[h0] write
    uint2 s_cur  = Sr[h0*W4];
    e1row(h0-1, 2,3,0, 3, false);
    e1row(h0+0, 3,0,1, 0, true);
    double locA = 0.0, locB = 0.0;
#pragma unroll
    for (int rr = 0; rr < 8; ++rr){
        int r = h0 + rr;
        uint2 cw_nxt = cw_cur, s_nxt = s_cur;
        if (rr < 7){                           // load C[r+1] BEFORE E1B[r+1] write
            cw_nxt = Cr[(r+1)*W4];
            s_nxt  = Sr[(r+1)*W4];
        }
        ldmg(r+2, (rr+2)&3);
        e1row(r+1, rr&3, (rr+1)&3, (rr+2)&3, (rr+1)&3, rr < 7);
        uint2 v2 = pmin2(mnE[(rr+3)&3], pmin2(mnE[rr&3], mnE[(rr+1)&3]));
        E2w[r*W4] = hmin2(v2, lane);
        uint2 vv = pmax2(mxE[(rr+3)&3], pmax2(mxE[rr&3], mxE[(rr+1)&3]));
        uint2 ovw = hmax2(vv, lane);           // O_{i+1} = dilate(E1)
        uint2 vi = pmax2(mxB[(rr+3)&3], pmax2(mxB[rr&3], mxB[(rr+1)&3]));
        uint2 oiw = hmax2(vi, lane);           // O_i = dilate(X)
        // ---- update i (identical op order to verified upd_k) ----
        float4 o = cvt4(oiw.x, oiw.y);
        float4 a = cvt4(cw_cur.x, cw_cur.y);
        float4 s = cvt4(s_cur.x, s_cur.y);
        float4 up; float dl;
        dl = lk(a.x-o.x); up.x = lk(dl - s.x*dl)*lr0; s.x += up.x;
        dl = lk(a.y-o.y); up.y = lk(dl - s.y*dl)*lr0; s.y += up.y;
        dl = lk(a.z-o.z); up.z = lk(dl - s.z*dl)*lr0; s.z += up.z;
        dl = lk(a.w-o.w); up.w = lk(dl - s.w*dl)*lr0; s.w += up.w;
        if constexpr(FIRST)
            locA += (double)(fabsf(s.x)+fabsf(s.y)+fabsf(s.z)+fabsf(s.w));
        else
            locA += (double)(fabsf(up.x)+fabsf(up.y)+fabsf(up.z)+fabsf(up.w));
        h4 s1h = f4toh4(s);                    // the inter-dispatch fp16 rounding
        Spw[r*W4] = __builtin_bit_cast(uint2, s1h);
        // ---- update i+1 ----
        float4 s2 = h4tof4(s1h);
        float4 o1 = cvt4(ovw.x, ovw.y);
        float4 a1 = cvt4(rawC[rr&3].x, rawC[rr&3].y);   // C_{i+1} = X[d][r]
        dl = lk(a1.x-o1.x); up.x = lk(dl - s2.x*dl)*lr1; s2.x += up.x;
        dl = lk(a1.y-o1.y); up.y = lk(dl - s2.y*dl)*lr1; s2.y += up.y;
        dl = lk(a1.z-o1.z); up.z = lk(dl - s2.z*dl)*lr1; s2.z += up.z;
        dl = lk(a1.w-o1.w); up.w = lk(dl - s2.w*dl)*lr1; s2.w += up.w;
        locB += (double)(fabsf(up.x)+fabsf(up.y)+fabsf(up.z)+fabsf(up.w));
        Sw[r*W4] = __builtin_bit_cast(uint2, f4toh4(s2));
        cw_cur = cw_nxt; s_cur = s_nxt;
    }
#pragma unroll
    for (int o = 32; o; o >>= 1){ locA += __shfl_down(locA,o); locB += __shfl_down(locB,o); }
    if (lane == 0){ smA[wv] = locA; smB[wv] = locB; }
    __syncthreads();
    if (tid == 0){
        nA[bi] = smA[0]+smA[1]+smA[2]+smA[3];
        nB[bi] = smB[0]+smB[1]+smB[2]+smB[3];
    }
}

// finish_k: if not frozen after all 20 iters: out = 1.1 * (norm18 froze ? Sprev : S)
__global__ __launch_bounds__(256) void finish_k(const h4* __restrict__ Sb,
                                                const h4* __restrict__ Spb,
                                                const double* __restrict__ g18,
                                                const int* __restrict__ frozen,
                                                float* __restrict__ outp){
    if (*frozen) return;
    __shared__ double sw[4];
    int tid = threadIdx.x, lane = tid & 63, wv = tid >> 6;
    double v = 0.0;
#pragma unroll
    for (int j = 0; j < GBLK/256; ++j) v += g18[tid + 256*j];
#pragma unroll
    for (int o = 32; o; o >>= 1) v += __shfl_down(v, o);
    if (lane == 0) sw[wv] = v;
    __syncthreads();
    bool f18 = (float)((sw[0]+sw[1]+sw[2]+sw[3]) / (double)NTOT) < STOPF;
    Geo g = mkgeo(tid, blockIdx.x);
    const h4* Sf = (f18 ? Spb : Sb) + g.pbase;
    float4* O = (float4*)outp + g.pbase;
#pragma unroll
    for (int r = 0; r < ROWS; ++r){
        float4 s = h4tof4(Sf[(g.h0+r)*W4]);
        O[(g.h0+r)*W4] = make_float4(1.1f*s.x, 1.1f*s.y, 1.1f*s.z, 1.1f*s.w);
    }
}

// ===================== FALLBACK PATH (round-6, verified) ====================
__device__ __forceinline__ void phase_f32_erode(
    const float4* __restrict__ Xm, const float4* __restrict__ Xc, const float4* __restrict__ Xp,
    bool pm, bool pp, h4* __restrict__ Ep, int h0, int lane)
{
    const float INF = __builtin_inff();
    float4 dmn[4];
    auto ldrow = [&](int j){
        int s = j & 3; int h = h0 - 1 + j;
        if (h >= 0 && h < H_){
            float4 v = ld4(Xc + h*W4); float4 mn = v;
            if (pm){ mn = mn4(mn, ld4(Xm + h*W4)); }
            if (pp){ mn = mn4(mn, ld4(Xp + h*W4)); }
            dmn[s] = mn;
        } else dmn[s] = make_float4(INF,INF,INF,INF);
    };
    ldrow(0); ldrow(1); ldrow(2);
#pragma unroll
    for (int r = 0; r < ROWS; ++r){
        if (r + 3 <= ROWS + 1) ldrow(r+3);
        float4 vmn = mn4(dmn[r&3], mn4(dmn[(r+1)&3], dmn[(r+2)&3]));
        float lmn = __shfl_up(vmn.w,1);   if (lane == 0)  lmn = INF;
        float rmn = __shfl_down(vmn.x,1); if (lane == 63) rmn = INF;
        float4 e;
        e.x = fminf(lmn,  fminf(vmn.x,vmn.y));
        e.y = fminf(vmn.x,fminf(vmn.y,vmn.z));
        e.z = fminf(vmn.y,fminf(vmn.z,vmn.w));
        e.w = fminf(vmn.z,fminf(vmn.w,rmn));
        st4(Ep + (h0+r)*W4, e);
    }
}

template<int MODE, int R, typename CT>
__device__ __forceinline__ double phase_pk(
    const uint2* __restrict__ Xm, const uint2* __restrict__ Xc, const uint2* __restrict__ Xp,
    bool pm, bool pp,
    uint2* __restrict__ Ep, const CT* __restrict__ Cp, h4* __restrict__ Sp,
    float lr, int h0, int lane)
{
    uint2 rmn[4], rmx[4];
    double loc = 0.0;
    auto ldrow = [&](int j){
        int s = j & 3; int h = h0 - 1 + j;
        if (h >= 0 && h < H_){
            uint2 v = *(Xc + h*W4); uint2 mn = v, mx = v;
            if (pm){ uint2 u = *(Xm + h*W4); mn = pmin2(mn,u); mx = pmax2(mx,u); }
            if (pp){ uint2 u = *(Xp + h*W4); mn = pmin2(mn,u); mx = pmax2(mx,u); }
            rmn[s] = mn; rmx[s] = mx;
        } else {
            rmn[s] = make_uint2(PINF,PINF);
            rmx[s] = make_uint2(NINF,NINF);
        }
    };
    ldrow(0); ldrow(1); ldrow(2);
    float4 a_cur = ld4(Cp + h0*W4);
    float4 s_cur = make_float4(0,0,0,0);
    if constexpr(MODE >= 2) s_cur = ld4(Sp + h0*W4);
#pragma unroll
    for (int r = 0; r < R; ++r){
        if (r + 3 <= R + 1) ldrow(r+3);
        float4 a_nxt = a_cur, s_nxt = s_cur;
        if (r + 1 < R){
            a_nxt = ld4(Cp + (h0+r+1)*W4);
            if constexpr(MODE >= 2) s_nxt = ld4(Sp + (h0+r+1)*W4);
        }
        uint2 vmn = pmin2(rmn[r&3], pmin2(rmn[(r+1)&3], rmn[(r+2)&3]));
        uint2 vmx = pmax2(rmx[r&3], pmax2(rmx[(r+1)&3], rmx[(r+2)&3]));
        uint2 ew = hmin2(vmn, lane);
        *(Ep + (h0+r)*W4) = ew;
        uint2 ow = hmax2(vmx, lane);
        float4 o = cvt4(ow.x, ow.y);
        float4 a = a_cur;
        if constexpr(MODE == 1){
            float4 s0;
            s0.x = lk(a.x-o.x); s0.y = lk(a.y-o.y);
            s0.z = lk(a.z-o.z); s0.w = lk(a.w-o.w);
            st4(Sp + (h0+r)*W4, s0);
        } else {
            float4 s = s_cur;
            float4 up; float dl;
            dl = lk(a.x-o.x); up.x = lk(dl - s.x*dl)*lr; s.x += up.x;
            dl = lk(a.y-o.y); up.y = lk(dl - s.y*dl)*lr; s.y += up.y;
            dl = lk(a.z-o.z); up.z = lk(dl - s.z*dl)*lr; s.z += up.z;
            dl = lk(a.w-o.w); up.w = lk(dl - s.w*dl)*lr; s.w += up.w;
            st4(Sp + (h0+r)*W4, s);
            if constexpr(MODE == 2)
                loc += (double)(fabsf(s.x)+fabsf(s.y)+fabsf(s.z)+fabsf(s.w));
            else
                loc += (double)(fabsf(up.x)+fabsf(up.y)+fabsf(up.z)+fabsf(up.w));
        }
        a_cur = a_nxt; s_cur = s_nxt;
    }
    return loc;
}

__global__ __launch_bounds__(256) void p0_k(const float* __restrict__ img0,
                                            h4* __restrict__ R0,
                                            int* __restrict__ frozen){
    if (blockIdx.x == 0 && threadIdx.x == 0) *frozen = 0;
    Geo g = mkgeo(threadIdx.x, blockIdx.x);
    const float4* Xc = (const float4*)img0 + g.pbase;
    phase_f32_erode(Xc-PS, Xc, Xc+PS, g.pm, g.pp, R0+g.pbase, g.h0, g.lane);
}

__global__ __launch_bounds__(256) void p1_k(const h4* __restrict__ R0,
                                            const float* __restrict__ img0,
                                            h4* __restrict__ R1,
                                            h4* __restrict__ S){
    Geo g = mkgeo(threadIdx.x, blockIdx.x);
    const uint2* Xc = (const uint2*)R0 + g.pbase;
    phase_pk<1,ROWS,float4>(Xc-PS, Xc, Xc+PS, g.pm, g.pp, (uint2*)R1 + g.pbase,
                            (const float4*)img0 + g.pbase, S + g.pbase, 0.f, g.h0, g.lane);
}

template<int MODE>
__global__ __launch_bounds__(256) void upd_k(const h4* __restrict__ Xb,
                                             const h4* __restrict__ Cb,
                                             h4* __restrict__ Eb,
                                             h4* __restrict__ Sb,
                                             const double* __restrict__ pr,
                                             double* __restrict__ pw,
                                             int* __restrict__ frozen,
                                             float* __restrict__ outp,
                                             float lr){
    if (*frozen) return;
    __shared__ double sm[4];
    int tid = threadIdx.x;
    int lane = tid & 63, wv = tid >> 6;
    if constexpr(MODE == 3){
        double v = 0.0;
#pragma unroll
        for (int j = 0; j < GBLK/256; ++j) v += pr[tid + 256*j];
#pragma unroll
        for (int o = 32; o; o >>= 1) v += __shfl_down(v, o);
        if (lane == 0) sm[wv] = v;
        __syncthreads();
        double tot = sm[0] + sm[1] + sm[2] + sm[3];
        if ((float)(tot / (double)NTOT) < STOPF){
            if (tid == 0) *frozen = 1;
            Geo g = mkgeo(tid, blockIdx.x);
            const h4* Sp = Sb + g.pbase;
            float4* O = (float4*)outp + g.pbase;
#pragma unroll
            for (int r = 0; r < ROWS; ++r){
                float4 s = h4tof4(Sp[(g.h0+r)*W4]);
                O[(g.h0+r)*W4] = make_float4(1.1f*s.x, 1.1f*s.y, 1.1f*s.z, 1.1f*s.w);
            }
            return;
        }
        __syncthreads();
    }
    Geo g = mkgeo(tid, blockIdx.x);
    const uint2* Xc = (const uint2*)Xb + g.pbase;
    double loc = phase_pk<MODE,ROWS,h4>(Xc-PS, Xc, Xc+PS, g.pm, g.pp,
                                        (uint2*)Eb + g.pbase, Cb + g.pbase, Sb + g.pbase,
                                        lr, g.h0, g.lane);
#pragma unroll
    for (int o = 32; o; o >>= 1) loc += __shfl_down(loc, o);
    if (lane == 0) sm[wv] = loc;
    __syncthreads();
    if (tid == 0) pw[blockIdx.x] = sm[0]+sm[1]+sm[2]+sm[3];
}

__global__ __launch_bounds__(256) void tail_k(h4* __restrict__ rg0,
                                              h4* __restrict__ rg1,
                                              h4* __restrict__ rg2,
                                              h4* __restrict__ S,
                                              float* __restrict__ outp,
                                              const double* __restrict__ pr0,
                                              double* __restrict__ tp0,
                                              double* __restrict__ tp1,
                                              const int* __restrict__ frozen){
    if (*frozen) return;
    cooperative_groups::grid_group gg = cooperative_groups::this_grid();
    __shared__ double sm[4];
    int tid = threadIdx.x, lane = tid & 63, wv = tid >> 6;
    int bi = blockIdx.x;
    int d = bi >> 3, b = (bi >> 2) & 1, q = bi & 3;
    int h0 = q*64 + wv*16;
    size_t pbase = ((size_t)(b*128 + d))*PS + (size_t)lane;
    bool pm = d > 0, pp = d < 127;
    const double* pr = pr0; int prn = GBLK;
    double* tpw = tp0;
    for (int i = TSTART; i < 20; ++i){
        double v = 0.0;
        for (int j = 0; j < prn/256; ++j) v += pr[tid + 256*j];
#pragma unroll
        for (int o = 32; o; o >>= 1) v += __shfl_down(v, o);
        if (lane == 0) sm[wv] = v;
        __syncthreads();
        double tot = sm[0] + sm[1] + sm[2] + sm[3];
        if ((float)(tot / (double)NTOT) < STOPF) break;
        __syncthreads();
        int xs = (i+1)%3, es = (i+2)%3, cs = i%3;
        h4* X = xs==0 ? rg0 : (xs==1 ? rg1 : rg2);
        h4* E = es==0 ? rg0 : (es==1 ? rg1 : rg2);
        h4* C = cs==0 ? rg0 : (cs==1 ? rg1 : rg2);
        float lr = 0.1f * exp2f(-(float)(i >> 2));
        const uint2* Xc = (const uint2*)X + pbase;
        double loc = phase_pk<3,16,h4>(Xc-PS, Xc, Xc+PS, pm, pp, (uint2*)E + pbase,
                                       C + pbase, S + pbase, lr, h0, lane);
#pragma unroll
        for (int o = 32; o; o >>= 1) loc += __shfl_down(loc, o);
        if (lane == 0) sm[wv] = loc;
        __syncthreads();
        if (tid == 0) tpw[blockIdx.x] = sm[0]+sm[1]+sm[2]+sm[3];
        gg.sync();
        pr = tpw; prn = 1024;
        tpw = (tpw == tp0) ? tp1 : tp0;
    }
    const h4* Sp = S + pbase;
    float4* O = (float4*)outp + pbase;
#pragma unroll
    for (int r = 0; r < 16; ++r){
        float4 s = h4tof4(Sp[(h0+r)*W4]);
        O[(h0+r)*W4] = make_float4(1.1f*s.x, 1.1f*s.y, 1.1f*s.z, 1.1f*s.w);
    }
}

__global__ __launch_bounds__(256) void scale_k(const h4* __restrict__ S,
                                               float* __restrict__ out){
    int t = blockIdx.x*256 + threadIdx.x;
#pragma unroll
    for (int c = 0; c < 4; ++c){
        int i = t + c*1048576;
        float4 s = ld4(S + i);
        float4 r = make_float4(1.1f*s.x, 1.1f*s.y, 1.1f*s.z, 1.1f*s.w);
        *(float4*)(out + (size_t)i*4) = r;
    }
}

extern "C" void kernel_launch(void* const* d_in, const int* in_sizes, int n_in,
                              void* d_out, int out_size, void* d_ws, size_t ws_size,
                              hipStream_t stream){
    const float* img0 = (const float*)d_in[0];
    float* out = (float*)d_out;
    char* ws = (char*)d_ws;
    size_t volh = (size_t)NTOT * 2;            // fp16 volume: 33.5 MB
    h4* ring[3] = { (h4*)ws, (h4*)(ws + volh), (h4*)(ws + 2*volh) };
    h4* S       = (h4*)(ws + 3*volh);
    double* parts[2] = { (double*)(ws + 4*volh), (double*)(ws + 4*volh) + GBLK };
    int* frozen = (int*)(ws + 4*volh + 2*GBLK*sizeof(double));
    double* tp0 = (double*)(ws + 4*volh + 2*GBLK*sizeof(double) + 256);
    double* tp1 = tp0 + 1024;
    // fused-path extras
    h4* Sprev   = (h4*)(ws + 4*volh + 65536);
    double* nrm = (double*)(ws + 4*volh + 65536 + volh);
    size_t NEED = 4*volh + 65536 + volh + (size_t)20*GBLK*sizeof(double);

    dim3 blk(256), grd(GBLK);
    if (ws_size >= NEED){
        // ---- fused path: init + 10 pair kernels + finish ----
        hipLaunchKernelGGL(init_k, grd, blk, 0, stream, img0, ring[0], ring[1], S, frozen);
        for (int p = 0; p < 10; ++p){
            h4* X  = (p & 1) ? ring[2] : ring[1];
            h4* E2 = (p & 1) ? ring[1] : ring[2];
            float l0 = (float)(0.1 * pow(0.5, (double)((2*p) / 4)));
            float l1 = (float)(0.1 * pow(0.5, (double)((2*p+1) / 4)));
            double* nA = nrm + (size_t)(2*p)   * GBLK;
            double* nB = nrm + (size_t)(2*p+1) * GBLK;
            if (p == 0){
                hipLaunchKernelGGL((pair_k<true,true>), grd, blk, 0, stream,
                                   X, ring[0], E2, S, Sprev, nA, nB,
                                   (const double*)nullptr, (const double*)nullptr,
                                   frozen, out, l0, l1);
            } else {
                const double* g2 = nrm + (size_t)(2*p-2) * GBLK;
                const double* g1 = nrm + (size_t)(2*p-1) * GBLK;
                hipLaunchKernelGGL((pair_k<false,false>), grd, blk, 0, stream,
                                   X, ring[0], E2, S, Sprev, nA, nB,
                                   g2, g1, frozen, out, l0, l1);
            }
        }
        hipLaunchKernelGGL(finish_k, grd, blk, 0, stream,
                           S, Sprev, nrm + (size_t)18*GBLK, frozen, out);
        return;
    }

    // ---- fallback: verified round-6 path ----
    hipLaunchKernelGGL(p0_k, grd, blk, 0, stream, img0, ring[0], frozen);
    hipLaunchKernelGGL(p1_k, grd, blk, 0, stream, ring[0], img0, ring[1], S);
    for (int i = 0; i < TSTART; ++i){
        h4* C = ring[i % 3];
        h4* X = ring[(i+1) % 3];
        h4* E = ring[(i+2) % 3];
        float lr = (float)(0.1 * pow(0.5, (double)(i / 4)));
        double* pw = parts[i & 1];
        double* pr = parts[1 - (i & 1)];
        if (i == 0)
            hipLaunchKernelGGL((upd_k<2>), grd, blk, 0, stream, X, C, E, S, pr, pw, frozen, out, lr);
        else
            hipLaunchKernelGGL((upd_k<3>), grd, blk, 0, stream, X, C, E, S, pr, pw, frozen, out, lr);
    }
    h4* a_r0 = ring[0]; h4* a_r1 = ring[1]; h4* a_r2 = ring[2];
    h4* a_S = S; float* a_out = out;
    const double* a_pr0 = parts[1 - (TSTART & 1)];
    double* a_tp0 = tp0; double* a_tp1 = tp1; int* a_fz = frozen;
    void* args[9] = { &a_r0, &a_r1, &a_r2, &a_S, &a_out, &a_pr0, &a_tp0, &a_tp1, &a_fz };
    hipError_t ce = hipLaunchCooperativeKernel((const void*)tail_k, dim3(1024), blk,
                                               args, 0u, stream);
    if (ce != hipSuccess){
        for (int i = TSTART; i < 20; ++i){
            h4* C = ring[i % 3];
            h4* X = ring[(i+1) % 3];
            h4* E = ring[(i+2) % 3];
            float lr = (float)(0.1 * pow(0.5, (double)(i / 4)));
            double* pw = parts[i & 1];
            double* pr = parts[1 - (i & 1)];
            hipLaunchKernelGGL((upd_k<3>), grd, blk, 0, stream, X, C, E, S, pr, pw, frozen, out, lr);
        }
        hipLaunchKernelGGL(scale_k, dim3(4096), blk, 0, stream, S, out);
    }
}

// Round 9
// 300.660 us; speedup vs baseline: 1.0323x; 1.0323x over previous
//
#include <hip/hip_runtime.h>
#include <hip/hip_cooperative_groups.h>
#include <cmath>

#define D_ 128
#define H_ 256
#define W4 64                         // 4-elem groups per row (256 wide)
#define PS (H_*W4)                    // plane stride in groups (16384)
#define NTOT (2*128*256*256)
#define GBLK 2048                     // b(2)*d(128)*h-eighth(8)
#define ROWS 8                        // rows per thread (upd path)
#define TSTART 6                      // first coop-tail iteration
#define STOPF 1e-4f

typedef _Float16 h4 __attribute__((ext_vector_type(4)));
typedef _Float16 h2v __attribute__((ext_vector_type(2)));

__device__ __forceinline__ float lk(float x){ return x >= 0.f ? x : 0.01f*x; }
__device__ __forceinline__ float4 ld4(const float4* p){ return *p; }
__device__ __forceinline__ float4 ld4(const h4* p){
    h4 v = *p; return make_float4((float)v.x,(float)v.y,(float)v.z,(float)v.w); }
__device__ __forceinline__ void st4(h4* p, float4 v){
    h4 r; r.x=(_Float16)v.x; r.y=(_Float16)v.y; r.z=(_Float16)v.z; r.w=(_Float16)v.w; *p = r; }
__device__ __forceinline__ float4 h4tof4(h4 v){
    return make_float4((float)v.x,(float)v.y,(float)v.z,(float)v.w); }
__device__ __forceinline__ h4 f4toh4(float4 v){
    h4 r; r.x=(_Float16)v.x; r.y=(_Float16)v.y; r.z=(_Float16)v.z; r.w=(_Float16)v.w; return r; }

// ---- packed fp16 helpers: v_pk_min/max_f16 (selection ops -> bit-exact) ----
#define PINF 0x7C007C00u
#define NINF 0xFC00FC00u
__device__ __forceinline__ uint32_t pmin(uint32_t a, uint32_t b){
    h2v r = __builtin_elementwise_min(__builtin_bit_cast(h2v,a), __builtin_bit_cast(h2v,b));
    return __builtin_bit_cast(uint32_t, r); }
__device__ __forceinline__ uint32_t pmax(uint32_t a, uint32_t b){
    h2v r = __builtin_elementwise_max(__builtin_bit_cast(h2v,a), __builtin_bit_cast(h2v,b));
    return __builtin_bit_cast(uint32_t, r); }
__device__ __forceinline__ uint2 pmin2(uint2 a, uint2 b){
    return make_uint2(pmin(a.x,b.x), pmin(a.y,b.y)); }
__device__ __forceinline__ uint2 pmax2(uint2 a, uint2 b){
    return make_uint2(pmax(a.x,b.x), pmax(a.y,b.y)); }
__device__ __forceinline__ float4 cvt4(uint32_t w01, uint32_t w23){
    h2v a = __builtin_bit_cast(h2v, w01);
    h2v b = __builtin_bit_cast(h2v, w23);
    return make_float4((float)a.x, (float)a.y, (float)b.x, (float)b.y); }
__device__ __forceinline__ uint2 pk4(float4 v){      // f32x4 -> packed fp16 (RTN)
    return __builtin_bit_cast(uint2, f4toh4(v)); }

// horizontal (w-axis) window min/max on packed pairs (4 elems / lane)
__device__ __forceinline__ uint2 hmin2(uint2 v, int lane){
    uint32_t pw = __shfl_up(v.y,1);   if (lane == 0)  pw = PINF;
    uint32_t nw = __shfl_down(v.x,1); if (lane == 63) nw = PINF;
    uint32_t l01 = (pw  >> 16) | (v.x << 16);
    uint32_t l23 = (v.x >> 16) | (v.y << 16);
    uint32_t r23 = (v.y >> 16) | (nw  << 16);
    return make_uint2(pmin(pmin(l01,v.x),l23), pmin(pmin(l23,v.y),r23));
}
__device__ __forceinline__ uint2 hmax2(uint2 v, int lane){
    uint32_t pw = __shfl_up(v.y,1);   if (lane == 0)  pw = NINF;
    uint32_t nw = __shfl_down(v.x,1); if (lane == 63) nw = NINF;
    uint32_t l01 = (pw  >> 16) | (v.x << 16);
    uint32_t l23 = (v.x >> 16) | (v.y << 16);
    uint32_t r23 = (v.y >> 16) | (nw  << 16);
    return make_uint2(pmax(pmax(l01,v.x),l23), pmax(pmax(l23,v.y),r23));
}

// geometry: block bi covers (b, d, h-eighth); wave owns ROWS rows.
// h-eighth in LOW 3 bits -> d-neighbor blocks (share X planes) on same XCD.
struct Geo { int lane, h0; size_t pbase; bool pm, pp; };
__device__ __forceinline__ Geo mkgeo(int tid, int bi){
    Geo g;
    g.lane = tid & 63;
    int wv = tid >> 6;
    int q = bi & 7, d = (bi >> 3) & 127, b = bi >> 10;
    g.h0 = q*32 + wv*ROWS;
    g.pbase = ((size_t)(b*128 + d))*PS + (size_t)g.lane;
    g.pm = (d > 0); g.pp = (d < 127);
    return g;
}

// ===================== init_k (round-7, verified) ===========================
// R0 = erode(img0), R1 = erode(R0), S = leaky(img0 - dilate(R0)).
// fp16 rounding is monotone => fp16(min_f32(..)) == min_fp16(fp16(..)):
// round img0 once, morphology all-packed-fp16 -> bit-identical to p0+p1.
__global__ __launch_bounds__(256) void init_k(const float* __restrict__ img0,
                                              h4* __restrict__ R0,
                                              h4* __restrict__ R1,
                                              h4* __restrict__ Sb,
                                              int* __restrict__ frozen){
    if (blockIdx.x == 0 && threadIdx.x == 0) *frozen = 0;
    int tid = threadIdx.x, lane = tid & 63, wv = tid >> 6;
    int bi = blockIdx.x;
    int q = bi & 7, d = (bi >> 3) & 127, b = bi >> 10;
    int h0 = q*32 + wv*8;                      // multiple of 8 -> ring idx compile-time
    size_t pbase = ((size_t)(b*128 + d))*PS + (size_t)lane;
    bool dm1 = d >= 1, dm2 = d >= 2, dp1 = d <= 126, dp2 = d <= 125;
    const float4* Xc = (const float4*)img0 + pbase;
    uint2* E1w = (uint2*)R0 + pbase;
    uint2* E2w = (uint2*)R1 + pbase;
    h4*    Sw  = Sb + pbase;

    float4 rawC[4];
    uint2 mnA[4], mnB[4], mnC[4], mnE[4], mxE[4];

    auto ldmg = [&](int h, int sl){
        if (h >= 0 && h < H_){
            const float4* p = Xc + h*W4;
            float4 c4 = p[0]; rawC[sl] = c4;
            uint2 c = pk4(c4);
            uint2 xm1, xm2, xp1, xp2;
            if (dm1) xm1 = pk4(p[-(int)PS]);
            if (dm2) xm2 = pk4(p[-2*(int)PS]);
            if (dp1) xp1 = pk4(p[(int)PS]);
            if (dp2) xp2 = pk4(p[2*(int)PS]);
            uint2 mb = c;
            if (dm1) mb = pmin2(mb, xm1);
            if (dp1) mb = pmin2(mb, xp1);
            mnB[sl] = mb;
            if (dm1){ uint2 a = pmin2(xm1, c); if (dm2) a = pmin2(a, xm2); mnA[sl] = a; }
            if (dp1){ uint2 cc = pmin2(xp1, c); if (dp2) cc = pmin2(cc, xp2); mnC[sl] = cc; }
        } else {
            mnA[sl] = make_uint2(PINF,PINF); mnB[sl] = make_uint2(PINF,PINF);
            mnC[sl] = make_uint2(PINF,PINF);
            rawC[sl] = make_float4(0,0,0,0);
        }
    };
    auto e1row = [&](int e, int s0, int s1, int s2, int se, bool wr){
        if (e >= 0 && e < H_){
            uint2 vb = pmin2(mnB[s0], pmin2(mnB[s1], mnB[s2]));
            uint2 e1b = hmin2(vb, lane);
            uint2 mn = e1b, mx = e1b;
            if (dm1){
                uint2 va = pmin2(mnA[s0], pmin2(mnA[s1], mnA[s2]));
                uint2 e1a = hmin2(va, lane);
                mn = pmin2(mn, e1a); mx = pmax2(mx, e1a);
            }
            if (dp1){
                uint2 vc = pmin2(mnC[s0], pmin2(mnC[s1], mnC[s2]));
                uint2 e1c = hmin2(vc, lane);
                mn = pmin2(mn, e1c); mx = pmax2(mx, e1c);
            }
            mnE[se] = mn; mxE[se] = mx;
            if (wr) E1w[e*W4] = e1b;
        } else { mnE[se] = make_uint2(PINF,PINF); mxE[se] = make_uint2(NINF,NINF); }
    };

    ldmg(h0-2, 2); ldmg(h0-1, 3); ldmg(h0+0, 0); ldmg(h0+1, 1);
    e1row(h0-1, 2,3,0, 3, false);
    e1row(h0+0, 3,0,1, 0, true);
#pragma unroll
    for (int rr = 0; rr < 8; ++rr){
        int r = h0 + rr;
        ldmg(r+2, (rr+2)&3);
        e1row(r+1, rr&3, (rr+1)&3, (rr+2)&3, (rr+1)&3, rr < 7);
        uint2 v2 = pmin2(mnE[(rr+3)&3], pmin2(mnE[rr&3], mnE[(rr+1)&3]));
        E2w[r*W4] = hmin2(v2, lane);
        uint2 vv = pmax2(mxE[(rr+3)&3], pmax2(mxE[rr&3], mxE[(rr+1)&3]));
        uint2 ow = hmax2(vv, lane);
        float4 o = cvt4(ow.x, ow.y);
        float4 a = rawC[rr&3];                 // img0 in f32 (exact p1 semantics)
        float4 s0;
        s0.x = lk(a.x-o.x); s0.y = lk(a.y-o.y);
        s0.z = lk(a.z-o.z); s0.w = lk(a.w-o.w);
        st4(Sw + r*W4, s0);
    }
}

// ===================== deep-prefetch packed core ============================
// E = erode3(X) written out; O = dilate3(X) consumed inline. Same ops, same
// order as the verified round-6 core -> bit-identical numerics. Changes are
// SCHEDULING only: 6-slot X ring (prefetch distance ~3-4 rows, covers ~200cy
// L2 latency) and 2-deep C/S prefetch (named regs, compile-time indexing).
// MODE 2: update, norm=|S_new| (iter 0). MODE 3: update, norm=|up|.
template<int MODE, int R>
__device__ __forceinline__ double phase_pk(
    const uint2* __restrict__ Xm, const uint2* __restrict__ Xc, const uint2* __restrict__ Xp,
    bool pm, bool pp,
    uint2* __restrict__ Ep, const h4* __restrict__ Cp, h4* __restrict__ Sp,
    float lr, int h0, int lane)
{
    uint2 rmn[6], rmx[6];
    double loc = 0.0;
    auto ldrow = [&](int j){
        int s = j % 6; int h = h0 - 1 + j;
        if (h >= 0 && h < H_){
            uint2 v = *(Xc + h*W4); uint2 mn = v, mx = v;
            if (pm){ uint2 u = *(Xm + h*W4); mn = pmin2(mn,u); mx = pmax2(mx,u); }
            if (pp){ uint2 u = *(Xp + h*W4); mn = pmin2(mn,u); mx = pmax2(mx,u); }
            rmn[s] = mn; rmx[s] = mx;
        } else {
            rmn[s] = make_uint2(PINF,PINF);
            rmx[s] = make_uint2(NINF,NINF);
        }
    };
    // prologue: 5 row-merges in flight (rows h0-1 .. h0+3)
    ldrow(0); ldrow(1); ldrow(2); ldrow(3); ldrow(4);
    // C/S: 2-deep prefetch (named regs -> no scratch)
    float4 aC = ld4(Cp + h0*W4), aN1 = aC, aN2;
    float4 sC = ld4(Sp + h0*W4), sN1 = sC, sN2;
    if (R >= 2){ aN1 = ld4(Cp + (h0+1)*W4); sN1 = ld4(Sp + (h0+1)*W4); }
#pragma unroll
    for (int rr = 0; rr < R; ++rr){
        if (rr + 5 <= R + 1) ldrow(rr+5);              // distance-3..4 prefetch
        aN2 = aN1; sN2 = sN1;
        if (rr + 2 < R){
            aN2 = ld4(Cp + (h0+rr+2)*W4);
            sN2 = ld4(Sp + (h0+rr+2)*W4);
        }
        uint2 vmn = pmin2(rmn[rr%6], pmin2(rmn[(rr+1)%6], rmn[(rr+2)%6]));
        uint2 vmx = pmax2(rmx[rr%6], pmax2(rmx[(rr+1)%6], rmx[(rr+2)%6]));
        uint2 ew = hmin2(vmn, lane);
        *(Ep + (h0+rr)*W4) = ew;
        uint2 ow = hmax2(vmx, lane);
        float4 o = cvt4(ow.x, ow.y);
        float4 a = aC;
        float4 s = sC;
        float4 up; float dl;
        dl = lk(a.x-o.x); up.x = lk(dl - s.x*dl)*lr; s.x += up.x;
        dl = lk(a.y-o.y); up.y = lk(dl - s.y*dl)*lr; s.y += up.y;
        dl = lk(a.z-o.z); up.z = lk(dl - s.z*dl)*lr; s.z += up.z;
        dl = lk(a.w-o.w); up.w = lk(dl - s.w*dl)*lr; s.w += up.w;
        st4(Sp + (h0+rr)*W4, s);
        if constexpr(MODE == 2)
            loc += (double)(fabsf(s.x)+fabsf(s.y)+fabsf(s.z)+fabsf(s.w));
        else
            loc += (double)(fabsf(up.x)+fabsf(up.y)+fabsf(up.z)+fabsf(up.w));
        aC = aN1; sC = sN1; aN1 = aN2; sN1 = sN2;
    }
    return loc;
}

// Update phase i. On freeze detection: writes out = 1.1*S inline.
template<int MODE>   // 2 (i==0, norm=|S|) or 3 (i>0, norm=|up|)
__global__ __launch_bounds__(256) void upd_k(const h4* __restrict__ Xb,
                                             const h4* __restrict__ Cb,
                                             h4* __restrict__ Eb,
                                             h4* __restrict__ Sb,
                                             const double* __restrict__ pr,
                                             double* __restrict__ pw,
                                             int* __restrict__ frozen,
                                             float* __restrict__ outp,
                                             float lr){
    if (*frozen) return;                       // cheap short-circuit after stop
    __shared__ double sm[4];
    int tid = threadIdx.x;
    int lane = tid & 63, wv = tid >> 6;
    if constexpr(MODE == 3){
        double v = 0.0;
#pragma unroll
        for (int j = 0; j < GBLK/256; ++j) v += pr[tid + 256*j];
#pragma unroll
        for (int o = 32; o; o >>= 1) v += __shfl_down(v, o);
        if (lane == 0) sm[wv] = v;
        __syncthreads();
        double tot = sm[0] + sm[1] + sm[2] + sm[3];
        if ((float)(tot / (double)NTOT) < STOPF){
            if (tid == 0) *frozen = 1;         // benign multi-block same-value write
            Geo g = mkgeo(tid, blockIdx.x);    // inline final scale: out = 1.1*S
            const h4* Sp = Sb + g.pbase;
            float4* O = (float4*)outp + g.pbase;
#pragma unroll
            for (int r = 0; r < ROWS; ++r){
                float4 s = h4tof4(Sp[(g.h0+r)*W4]);
                O[(g.h0+r)*W4] = make_float4(1.1f*s.x, 1.1f*s.y, 1.1f*s.z, 1.1f*s.w);
            }
            return;
        }
        __syncthreads();                       // protect sm reuse below
    }
    Geo g = mkgeo(tid, blockIdx.x);
    const uint2* Xc = (const uint2*)Xb + g.pbase;
    double loc = phase_pk<MODE,ROWS>(Xc-PS, Xc, Xc+PS, g.pm, g.pp,
                                     (uint2*)Eb + g.pbase, Cb + g.pbase, Sb + g.pbase,
                                     lr, g.h0, g.lane);
#pragma unroll
    for (int o = 32; o; o >>= 1) loc += __shfl_down(loc, o);
    if (lane == 0) sm[wv] = loc;
    __syncthreads();
    if (tid == 0) pw[blockIdx.x] = sm[0]+sm[1]+sm[2]+sm[3];
}

// Cooperative tail: iterations TSTART..19 + finalize. Common case (already
// frozen): read one flag and exit, replacing 14 frozen launches + scale.
__global__ __launch_bounds__(256) void tail_k(h4* __restrict__ rg0,
                                              h4* __restrict__ rg1,
                                              h4* __restrict__ rg2,
                                              h4* __restrict__ S,
                                              float* __restrict__ outp,
                                              const double* __restrict__ pr0,
                                              double* __restrict__ tp0,
                                              double* __restrict__ tp1,
                                              const int* __restrict__ frozen){
    if (*frozen) return;                       // scale already done at freeze
    cooperative_groups::grid_group gg = cooperative_groups::this_grid();
    __shared__ double sm[4];
    int tid = threadIdx.x, lane = tid & 63, wv = tid >> 6;
    int bi = blockIdx.x;
    int d = bi >> 3, b = (bi >> 2) & 1, q = bi & 3;   // 1024 blocks, 16 rows/thread
    int h0 = q*64 + wv*16;
    size_t pbase = ((size_t)(b*128 + d))*PS + (size_t)lane;
    bool pm = d > 0, pp = d < 127;
    const double* pr = pr0; int prn = GBLK;
    double* tpw = tp0;
    for (int i = TSTART; i < 20; ++i){
        double v = 0.0;
        for (int j = 0; j < prn/256; ++j) v += pr[tid + 256*j];
#pragma unroll
        for (int o = 32; o; o >>= 1) v += __shfl_down(v, o);
        if (lane == 0) sm[wv] = v;
        __syncthreads();
        double tot = sm[0] + sm[1] + sm[2] + sm[3];
        if ((float)(tot / (double)NTOT) < STOPF) break;
        __syncthreads();
        int xs = (i+1)%3, es = (i+2)%3, cs = i%3;
        h4* X = xs==0 ? rg0 : (xs==1 ? rg1 : rg2);
        h4* E = es==0 ? rg0 : (es==1 ? rg1 : rg2);
        h4* C = cs==0 ? rg0 : (cs==1 ? rg1 : rg2);
        float lr = 0.1f * exp2f(-(float)(i >> 2));
        const uint2* Xc = (const uint2*)X + pbase;
        double loc = phase_pk<3,16>(Xc-PS, Xc, Xc+PS, pm, pp, (uint2*)E + pbase,
                                    C + pbase, S + pbase, lr, h0, lane);
#pragma unroll
        for (int o = 32; o; o >>= 1) loc += __shfl_down(loc, o);
        if (lane == 0) sm[wv] = loc;
        __syncthreads();
        if (tid == 0) tpw[blockIdx.x] = sm[0]+sm[1]+sm[2]+sm[3];
        gg.sync();
        pr = tpw; prn = 1024;
        tpw = (tpw == tp0) ? tp1 : tp0;
    }
    const h4* Sp = S + pbase;
    float4* O = (float4*)outp + pbase;
#pragma unroll
    for (int r = 0; r < 16; ++r){
        float4 s = h4tof4(Sp[(h0+r)*W4]);
        O[(h0+r)*W4] = make_float4(1.1f*s.x, 1.1f*s.y, 1.1f*s.z, 1.1f*s.w);
    }
}

// Fallback-only standalone scale (dt == 0 identically -> out = 1.1*S)
__global__ __launch_bounds__(256) void scale_k(const h4* __restrict__ S,
                                               float* __restrict__ out){
    int t = blockIdx.x*256 + threadIdx.x;
#pragma unroll
    for (int c = 0; c < 4; ++c){
        int i = t + c*1048576;
        float4 s = ld4(S + i);
        float4 r = make_float4(1.1f*s.x, 1.1f*s.y, 1.1f*s.z, 1.1f*s.w);
        *(float4*)(out + (size_t)i*4) = r;
    }
}

extern "C" void kernel_launch(void* const* d_in, const int* in_sizes, int n_in,
                              void* d_out, int out_size, void* d_ws, size_t ws_size,
                              hipStream_t stream){
    const float* img0 = (const float*)d_in[0];
    float* out = (float*)d_out;
    char* ws = (char*)d_ws;
    size_t volh = (size_t)NTOT * 2;            // fp16 volume: 33.5 MB
    h4* ring[3] = { (h4*)ws, (h4*)(ws + volh), (h4*)(ws + 2*volh) };
    h4* S       = (h4*)(ws + 3*volh);
    double* parts[2] = { (double*)(ws + 4*volh), (double*)(ws + 4*volh) + GBLK };
    int* frozen = (int*)(ws + 4*volh + 2*GBLK*sizeof(double));
    double* tp0 = (double*)(ws + 4*volh + 2*GBLK*sizeof(double) + 256);
    double* tp1 = tp0 + 1024;

    dim3 blk(256), grd(GBLK);
    // fused init: R0 = erode(img0); R1 = erode(R0); S = leaky(img0 - open(img0))
    hipLaunchKernelGGL(init_k, grd, blk, 0, stream, img0, ring[0], ring[1], S, frozen);

    // iterations 0..TSTART-1 as plain dispatches (kernel boundary = cheap barrier)
    for (int i = 0; i < TSTART; ++i){
        h4* C = ring[i % 3];
        h4* X = ring[(i+1) % 3];
        h4* E = ring[(i+2) % 3];
        float lr = (float)(0.1 * pow(0.5, (double)(i / 4)));
        double* pw = parts[i & 1];
        double* pr = parts[1 - (i & 1)];
        if (i == 0)
            hipLaunchKernelGGL((upd_k<2>), grd, blk, 0, stream, X, C, E, S, pr, pw, frozen, out, lr);
        else
            hipLaunchKernelGGL((upd_k<3>), grd, blk, 0, stream, X, C, E, S, pr, pw, frozen, out, lr);
    }

    // coop tail: iterations TSTART..19 + finalize (fast exit when frozen)
    h4* a_r0 = ring[0]; h4* a_r1 = ring[1]; h4* a_r2 = ring[2];
    h4* a_S = S; float* a_out = out;
    const double* a_pr0 = parts[1 - (TSTART & 1)];   // partials from i=TSTART-1
    double* a_tp0 = tp0; double* a_tp1 = tp1; int* a_fz = frozen;
    void* args[9] = { &a_r0, &a_r1, &a_r2, &a_S, &a_out, &a_pr0, &a_tp0, &a_tp1, &a_fz };
    hipError_t ce = hipLaunchCooperativeKernel((const void*)tail_k, dim3(1024), blk,
                                               args, 0u, stream);
    if (ce != hipSuccess){
        // fallback: plain dispatches for the remaining iterations
        for (int i = TSTART; i < 20; ++i){
            h4* C = ring[i % 3];
            h4* X = ring[(i+1) % 3];
            h4* E = ring[(i+2) % 3];
            float lr = (float)(0.1 * pow(0.5, (double)(i / 4)));
            double* pw = parts[i & 1];
            double* pr = parts[1 - (i & 1)];
            hipLaunchKernelGGL((upd_k<3>), grd, blk, 0, stream, X, C, E, S, pr, pw, frozen, out, lr);
        }
        hipLaunchKernelGGL(scale_k, dim3(4096), blk, 0, stream, S, out);
    }
}

// Round 10
// 292.202 us; speedup vs baseline: 1.0621x; 1.0289x over previous
//
#include <hip/hip_runtime.h>
#include <hip/hip_cooperative_groups.h>
#include <cmath>

#define D_ 128
#define H_ 256
#define W4 64                         // 4-elem groups per row (uint2 units)
#define W8 32                         // 8-elem groups per row (uint4 units)
#define PS (H_*W4)                    // plane stride in uint2 groups (16384)
#define PS8 (H_*W8)                   // plane stride in uint4 groups (8192)
#define NTOT (2*128*256*256)
#define GBLK 2048                     // b(2)*d(128)*h-eighth(8)
#define ROWS 8                        // rows per thread (upd path)
#define TSTART 6                      // first coop-tail iteration
#define STOPF 1e-4f

typedef _Float16 h4 __attribute__((ext_vector_type(4)));
typedef _Float16 h2v __attribute__((ext_vector_type(2)));

__device__ __forceinline__ float lk(float x){ return x >= 0.f ? x : 0.01f*x; }
__device__ __forceinline__ float4 ld4(const float4* p){ return *p; }
__device__ __forceinline__ float4 ld4(const h4* p){
    h4 v = *p; return make_float4((float)v.x,(float)v.y,(float)v.z,(float)v.w); }
__device__ __forceinline__ void st4(h4* p, float4 v){
    h4 r; r.x=(_Float16)v.x; r.y=(_Float16)v.y; r.z=(_Float16)v.z; r.w=(_Float16)v.w; *p = r; }
__device__ __forceinline__ float4 h4tof4(h4 v){
    return make_float4((float)v.x,(float)v.y,(float)v.z,(float)v.w); }
__device__ __forceinline__ h4 f4toh4(float4 v){
    h4 r; r.x=(_Float16)v.x; r.y=(_Float16)v.y; r.z=(_Float16)v.z; r.w=(_Float16)v.w; return r; }

// ---- packed fp16 helpers: v_pk_min/max_f16 (selection ops -> bit-exact) ----
#define PINF 0x7C007C00u
#define NINF 0xFC00FC00u
__device__ __forceinline__ uint32_t pmin(uint32_t a, uint32_t b){
    h2v r = __builtin_elementwise_min(__builtin_bit_cast(h2v,a), __builtin_bit_cast(h2v,b));
    return __builtin_bit_cast(uint32_t, r); }
__device__ __forceinline__ uint32_t pmax(uint32_t a, uint32_t b){
    h2v r = __builtin_elementwise_max(__builtin_bit_cast(h2v,a), __builtin_bit_cast(h2v,b));
    return __builtin_bit_cast(uint32_t, r); }
__device__ __forceinline__ uint2 pmin2(uint2 a, uint2 b){
    return make_uint2(pmin(a.x,b.x), pmin(a.y,b.y)); }
__device__ __forceinline__ uint2 pmax2(uint2 a, uint2 b){
    return make_uint2(pmax(a.x,b.x), pmax(a.y,b.y)); }
__device__ __forceinline__ uint4 pmin4u(uint4 a, uint4 b){
    return make_uint4(pmin(a.x,b.x),pmin(a.y,b.y),pmin(a.z,b.z),pmin(a.w,b.w)); }
__device__ __forceinline__ uint4 pmax4u(uint4 a, uint4 b){
    return make_uint4(pmax(a.x,b.x),pmax(a.y,b.y),pmax(a.z,b.z),pmax(a.w,b.w)); }
__device__ __forceinline__ float4 cvt4(uint32_t w01, uint32_t w23){
    h2v a = __builtin_bit_cast(h2v, w01);
    h2v b = __builtin_bit_cast(h2v, w23);
    return make_float4((float)a.x, (float)a.y, (float)b.x, (float)b.y); }
__device__ __forceinline__ uint2 pk4(float4 v){      // f32x4 -> packed fp16 (RTN)
    return __builtin_bit_cast(uint2, f4toh4(v)); }
__device__ __forceinline__ uint4 x32(uint4 v){       // lane <-> lane^32 exchange
    return make_uint4(__shfl_xor(v.x,32),__shfl_xor(v.y,32),
                      __shfl_xor(v.z,32),__shfl_xor(v.w,32)); }

// horizontal (w-axis) 3-window on uint2 pairs (old 4-elem path, tail/fallback)
__device__ __forceinline__ uint2 hmin2(uint2 v, int lane){
    uint32_t pw = __shfl_up(v.y,1);   if (lane == 0)  pw = PINF;
    uint32_t nw = __shfl_down(v.x,1); if (lane == 63) nw = PINF;
    uint32_t l01 = (pw  >> 16) | (v.x << 16);
    uint32_t l23 = (v.x >> 16) | (v.y << 16);
    uint32_t r23 = (v.y >> 16) | (nw  << 16);
    return make_uint2(pmin(pmin(l01,v.x),l23), pmin(pmin(l23,v.y),r23));
}
__device__ __forceinline__ uint2 hmax2(uint2 v, int lane){
    uint32_t pw = __shfl_up(v.y,1);   if (lane == 0)  pw = NINF;
    uint32_t nw = __shfl_down(v.x,1); if (lane == 63) nw = NINF;
    uint32_t l01 = (pw  >> 16) | (v.x << 16);
    uint32_t l23 = (v.x >> 16) | (v.y << 16);
    uint32_t r23 = (v.y >> 16) | (nw  << 16);
    return make_uint2(pmax(pmax(l01,v.x),l23), pmax(pmax(l23,v.y),r23));
}

// horizontal 3-window on uint4 (8 elems / lane, 32 lanes = full 256-wide row)
__device__ __forceinline__ uint4 hwin_min4(uint4 v, int wl){
    uint32_t ld = __shfl_up(v.w,1);   if (wl == 0)  ld = PINF;  // lanes 0,32 masked
    uint32_t ra = __shfl_down(v.x,1); if (wl == 31) ra = PINF;  // lanes 31,63 masked
    uint32_t s0 = (ld >> 16) | (v.x << 16);
    uint32_t s1 = (v.x >> 16) | (v.y << 16);
    uint32_t s2 = (v.y >> 16) | (v.z << 16);
    uint32_t s3 = (v.z >> 16) | (v.w << 16);
    uint32_t s4 = (v.w >> 16) | (ra << 16);
    return make_uint4(pmin(s0,pmin(v.x,s1)), pmin(s1,pmin(v.y,s2)),
                      pmin(s2,pmin(v.z,s3)), pmin(s3,pmin(v.w,s4)));
}
__device__ __forceinline__ uint4 hwin_max4(uint4 v, int wl){
    uint32_t ld = __shfl_up(v.w,1);   if (wl == 0)  ld = NINF;
    uint32_t ra = __shfl_down(v.x,1); if (wl == 31) ra = NINF;
    uint32_t s0 = (ld >> 16) | (v.x << 16);
    uint32_t s1 = (v.x >> 16) | (v.y << 16);
    uint32_t s2 = (v.y >> 16) | (v.z << 16);
    uint32_t s3 = (v.z >> 16) | (v.w << 16);
    uint32_t s4 = (v.w >> 16) | (ra << 16);
    return make_uint4(pmax(s0,pmax(v.x,s1)), pmax(s1,pmax(v.y,s2)),
                      pmax(s2,pmax(v.z,s3)), pmax(s3,pmax(v.w,s4)));
}

// old geometry (detect-scale / tail / fallback): lane owns 4-elem group
struct Geo { int lane, h0; size_t pbase; bool pm, pp; };
__device__ __forceinline__ Geo mkgeo(int tid, int bi){
    Geo g;
    g.lane = tid & 63;
    int wv = tid >> 6;
    int q = bi & 7, d = (bi >> 3) & 127, b = bi >> 10;
    g.h0 = q*32 + wv*ROWS;
    g.pbase = ((size_t)(b*128 + d))*PS + (size_t)g.lane;
    g.pm = (d > 0); g.pp = (d < 127);
    return g;
}

// ===================== init_k (round-7, verified x2) ========================
// R0 = erode(img0), R1 = erode(R0), S = leaky(img0 - dilate(R0)).
// fp16 rounding is monotone => fp16(min_f32(..)) == min_fp16(fp16(..)).
__global__ __launch_bounds__(256) void init_k(const float* __restrict__ img0,
                                              h4* __restrict__ R0,
                                              h4* __restrict__ R1,
                                              h4* __restrict__ Sb,
                                              int* __restrict__ frozen){
    if (blockIdx.x == 0 && threadIdx.x == 0) *frozen = 0;
    int tid = threadIdx.x, lane = tid & 63, wv = tid >> 6;
    int bi = blockIdx.x;
    int q = bi & 7, d = (bi >> 3) & 127, b = bi >> 10;
    int h0 = q*32 + wv*8;
    size_t pbase = ((size_t)(b*128 + d))*PS + (size_t)lane;
    bool dm1 = d >= 1, dm2 = d >= 2, dp1 = d <= 126, dp2 = d <= 125;
    const float4* Xc = (const float4*)img0 + pbase;
    uint2* E1w = (uint2*)R0 + pbase;
    uint2* E2w = (uint2*)R1 + pbase;
    h4*    Sw  = Sb + pbase;

    float4 rawC[4];
    uint2 mnA[4], mnB[4], mnC[4], mnE[4], mxE[4];

    auto ldmg = [&](int h, int sl){
        if (h >= 0 && h < H_){
            const float4* p = Xc + h*W4;
            float4 c4 = p[0]; rawC[sl] = c4;
            uint2 c = pk4(c4);
            uint2 xm1, xm2, xp1, xp2;
            if (dm1) xm1 = pk4(p[-(int)PS]);
            if (dm2) xm2 = pk4(p[-2*(int)PS]);
            if (dp1) xp1 = pk4(p[(int)PS]);
            if (dp2) xp2 = pk4(p[2*(int)PS]);
            uint2 mb = c;
            if (dm1) mb = pmin2(mb, xm1);
            if (dp1) mb = pmin2(mb, xp1);
            mnB[sl] = mb;
            if (dm1){ uint2 a = pmin2(xm1, c); if (dm2) a = pmin2(a, xm2); mnA[sl] = a; }
            if (dp1){ uint2 cc = pmin2(xp1, c); if (dp2) cc = pmin2(cc, xp2); mnC[sl] = cc; }
        } else {
            mnA[sl] = make_uint2(PINF,PINF); mnB[sl] = make_uint2(PINF,PINF);
            mnC[sl] = make_uint2(PINF,PINF);
            rawC[sl] = make_float4(0,0,0,0);
        }
    };
    auto e1row = [&](int e, int s0, int s1, int s2, int se, bool wr){
        if (e >= 0 && e < H_){
            uint2 vb = pmin2(mnB[s0], pmin2(mnB[s1], mnB[s2]));
            uint2 e1b = hmin2(vb, lane);
            uint2 mn = e1b, mx = e1b;
            if (dm1){
                uint2 va = pmin2(mnA[s0], pmin2(mnA[s1], mnA[s2]));
                uint2 e1a = hmin2(va, lane);
                mn = pmin2(mn, e1a); mx = pmax2(mx, e1a);
            }
            if (dp1){
                uint2 vc = pmin2(mnC[s0], pmin2(mnC[s1], mnC[s2]));
                uint2 e1c = hmin2(vc, lane);
                mn = pmin2(mn, e1c); mx = pmax2(mx, e1c);
            }
            mnE[se] = mn; mxE[se] = mx;
            if (wr) E1w[e*W4] = e1b;
        } else { mnE[se] = make_uint2(PINF,PINF); mxE[se] = make_uint2(NINF,NINF); }
    };

    ldmg(h0-2, 2); ldmg(h0-1, 3); ldmg(h0+0, 0); ldmg(h0+1, 1);
    e1row(h0-1, 2,3,0, 3, false);
    e1row(h0+0, 3,0,1, 0, true);
#pragma unroll
    for (int rr = 0; rr < 8; ++rr){
        int r = h0 + rr;
        ldmg(r+2, (rr+2)&3);
        e1row(r+1, rr&3, (rr+1)&3, (rr+2)&3, (rr+1)&3, rr < 7);
        uint2 v2 = pmin2(mnE[(rr+3)&3], pmin2(mnE[rr&3], mnE[(rr+1)&3]));
        E2w[r*W4] = hmin2(v2, lane);
        uint2 vv = pmax2(mxE[(rr+3)&3], pmax2(mxE[rr&3], mxE[(rr+1)&3]));
        uint2 ow = hmax2(vv, lane);
        float4 o = cvt4(ow.x, ow.y);
        float4 a = rawC[rr&3];
        float4 s0;
        s0.x = lk(a.x-o.x); s0.y = lk(a.y-o.y);
        s0.z = lk(a.z-o.z); s0.w = lk(a.w-o.w);
        st4(Sw + r*W4, s0);
    }
}

// ===================== WIDE packed core (16B loads/stores) ==================
// Lane = (rl = lane>>5 row parity, wl = lane&31 column); lane owns 8 fp16
// (one uint4, 16 B). 32 lanes span the full 256-wide row; wave processes a
// row-PAIR per step, 4 pairs = 8 rows. Vertical neighbors via shfl_xor(32)
// with sender-side select. Same min/max selections + identical per-element
// f32 update chain -> bit-identical results; only memory width changes.
// MODE 2: norm=|S_new| (iter 0). MODE 3: norm=|up|.
template<int MODE>
__device__ __forceinline__ double phase_wide(
    const uint4* __restrict__ Xm8, const uint4* __restrict__ Xc8, const uint4* __restrict__ Xp8,
    bool pm, bool pp,
    uint4* __restrict__ Ep8, const uint4* __restrict__ Cp8, uint4* __restrict__ Sp8,
    float lr, int h0, int rl, int wl)
{
    uint4 mn[4], mx[4];
    double loc = 0.0;
    const uint4 VPI = make_uint4(PINF,PINF,PINF,PINF);
    const uint4 VNI = make_uint4(NINF,NINF,NINF,NINF);
    // ldpair(j): own row r = h0+2j+rl -> slot (j+1)&3. Halo pairs load only
    // the needed half (j=-1: rl==1 row h0-1; j=4: rl==0 row h0+8).
    auto ldpair = [&](int j){
        int s = (j+1)&3;
        int r = h0 + 2*j + rl;
        bool ok = (r >= 0) && (r < H_);
        if (j == -1) ok = ok && (rl == 1);
        if (j == 4)  ok = ok && (rl == 0);
        if (ok){
            const uint4* p = Xc8 + r*W8;
            uint4 v = *p; uint4 a = v, b = v;
            if (pm){ uint4 u = *(Xm8 + r*W8); a = pmin4u(a,u); b = pmax4u(b,u); }
            if (pp){ uint4 u = *(Xp8 + r*W8); a = pmin4u(a,u); b = pmax4u(b,u); }
            mn[s] = a; mx[s] = b;
        } else { mn[s] = VPI; mx[s] = VNI; }
    };
    ldpair(-1); ldpair(0); ldpair(1);
#pragma unroll
    for (int rr = 0; rr < 4; ++rr){
        if (rr < 3) ldpair(rr+2);
        int sp = rr&3, so = (rr+1)&3, sn = (rr+2)&3;   // pair rr-1, rr, rr+1
        int r = h0 + 2*rr + rl;                        // this lane's output row
        // vertical exchange: sender-side select, then xor32
        uint4 up_mn = x32(rl ? mn[sp] : mn[so]);
        uint4 dn_mn = x32(rl ? mn[so] : mn[sn]);
        uint4 vmn = pmin4u(up_mn, pmin4u(mn[so], dn_mn));
        uint4 up_mx = x32(rl ? mx[sp] : mx[so]);
        uint4 dn_mx = x32(rl ? mx[so] : mx[sn]);
        uint4 vmx = pmax4u(up_mx, pmax4u(mx[so], dn_mx));
        // horizontal windows (2 shuffles per direction)
        uint4 ew = hwin_min4(vmn, wl);
        *(Ep8 + r*W8) = ew;
        uint4 ow = hwin_max4(vmx, wl);
        // S-update on 8 elems (two identical 4-elem chains, per-elem exact)
        uint4 cw = *(Cp8 + r*W8);
        uint4 sw = *(Sp8 + r*W8);
        float4 oL = cvt4(ow.x, ow.y), oH = cvt4(ow.z, ow.w);
        float4 aL = cvt4(cw.x, cw.y), aH = cvt4(cw.z, cw.w);
        float4 sL = cvt4(sw.x, sw.y), sH = cvt4(sw.z, sw.w);
        float4 up; float dl;
        dl = lk(aL.x-oL.x); up.x = lk(dl - sL.x*dl)*lr; sL.x += up.x;
        dl = lk(aL.y-oL.y); up.y = lk(dl - sL.y*dl)*lr; sL.y += up.y;
        dl = lk(aL.z-oL.z); up.z = lk(dl - sL.z*dl)*lr; sL.z += up.z;
        dl = lk(aL.w-oL.w); up.w = lk(dl - sL.w*dl)*lr; sL.w += up.w;
        if constexpr(MODE == 2)
            loc += (double)(fabsf(sL.x)+fabsf(sL.y)+fabsf(sL.z)+fabsf(sL.w));
        else
            loc += (double)(fabsf(up.x)+fabsf(up.y)+fabsf(up.z)+fabsf(up.w));
        dl = lk(aH.x-oH.x); up.x = lk(dl - sH.x*dl)*lr; sH.x += up.x;
        dl = lk(aH.y-oH.y); up.y = lk(dl - sH.y*dl)*lr; sH.y += up.y;
        dl = lk(aH.z-oH.z); up.z = lk(dl - sH.z*dl)*lr; sH.z += up.z;
        dl = lk(aH.w-oH.w); up.w = lk(dl - sH.w*dl)*lr; sH.w += up.w;
        if constexpr(MODE == 2)
            loc += (double)(fabsf(sH.x)+fabsf(sH.y)+fabsf(sH.z)+fabsf(sH.w));
        else
            loc += (double)(fabsf(up.x)+fabsf(up.y)+fabsf(up.z)+fabsf(up.w));
        uint2 pL = pk4(sL), pH = pk4(sH);
        *(Sp8 + r*W8) = make_uint4(pL.x, pL.y, pH.x, pH.y);
    }
    return loc;
}

// Update phase i (wide core). On freeze detection: out = 1.1*S inline.
template<int MODE>   // 2 (i==0) or 3 (i>0)
__global__ __launch_bounds__(256) void upd_k(const h4* __restrict__ Xb,
                                             const h4* __restrict__ Cb,
                                             h4* __restrict__ Eb,
                                             h4* __restrict__ Sb,
                                             const double* __restrict__ pr,
                                             double* __restrict__ pw,
                                             int* __restrict__ frozen,
                                             float* __restrict__ outp,
                                             float lr){
    if (*frozen) return;                       // cheap short-circuit after stop
    __shared__ double sm[4];
    int tid = threadIdx.x;
    int lane = tid & 63, wv = tid >> 6;
    if constexpr(MODE == 3){
        double v = 0.0;
#pragma unroll
        for (int j = 0; j < GBLK/256; ++j) v += pr[tid + 256*j];
#pragma unroll
        for (int o = 32; o; o >>= 1) v += __shfl_down(v, o);
        if (lane == 0) sm[wv] = v;
        __syncthreads();
        double tot = sm[0] + sm[1] + sm[2] + sm[3];
        if ((float)(tot / (double)NTOT) < STOPF){
            if (tid == 0) *frozen = 1;         // benign multi-block same-value write
            Geo g = mkgeo(tid, blockIdx.x);    // inline final scale: out = 1.1*S
            const h4* Sp = Sb + g.pbase;
            float4* O = (float4*)outp + g.pbase;
#pragma unroll
            for (int r = 0; r < ROWS; ++r){
                float4 s = h4tof4(Sp[(g.h0+r)*W4]);
                O[(g.h0+r)*W4] = make_float4(1.1f*s.x, 1.1f*s.y, 1.1f*s.z, 1.1f*s.w);
            }
            return;
        }
        __syncthreads();                       // protect sm reuse below
    }
    int bi = blockIdx.x;
    int q = bi & 7, d = (bi >> 3) & 127, b = bi >> 10;
    int rl = lane >> 5, wl = lane & 31;
    int h0 = q*32 + wv*8;
    size_t base8 = ((size_t)(b*128 + d))*PS8 + (size_t)wl;
    bool pm = d > 0, pp = d < 127;
    const uint4* Xc8 = (const uint4*)Xb + base8;
    double loc = phase_wide<MODE>(Xc8-PS8, Xc8, Xc8+PS8, pm, pp,
                                  (uint4*)Eb + base8, (const uint4*)Cb + base8,
                                  (uint4*)Sb + base8, lr, h0, rl, wl);
#pragma unroll
    for (int o = 32; o; o >>= 1) loc += __shfl_down(loc, o);
    if (lane == 0) sm[wv] = loc;
    __syncthreads();
    if (tid == 0) pw[blockIdx.x] = sm[0]+sm[1]+sm[2]+sm[3];
}

// ===================== tail/fallback core (round-6, verified) ===============
template<int MODE, int R>
__device__ __forceinline__ double phase_pk(
    const uint2* __restrict__ Xm, const uint2* __restrict__ Xc, const uint2* __restrict__ Xp,
    bool pm, bool pp,
    uint2* __restrict__ Ep, const h4* __restrict__ Cp, h4* __restrict__ Sp,
    float lr, int h0, int lane)
{
    uint2 rmn[4], rmx[4];
    double loc = 0.0;
    auto ldrow = [&](int j){
        int s = j & 3; int h = h0 - 1 + j;
        if (h >= 0 && h < H_){
            uint2 v = *(Xc + h*W4); uint2 mn = v, mx = v;
            if (pm){ uint2 u = *(Xm + h*W4); mn = pmin2(mn,u); mx = pmax2(mx,u); }
            if (pp){ uint2 u = *(Xp + h*W4); mn = pmin2(mn,u); mx = pmax2(mx,u); }
            rmn[s] = mn; rmx[s] = mx;
        } else {
            rmn[s] = make_uint2(PINF,PINF);
            rmx[s] = make_uint2(NINF,NINF);
        }
    };
    ldrow(0); ldrow(1); ldrow(2);
    float4 a_cur = ld4(Cp + h0*W4);
    float4 s_cur = ld4(Sp + h0*W4);
#pragma unroll
    for (int r = 0; r < R; ++r){
        if (r + 3 <= R + 1) ldrow(r+3);
        float4 a_nxt = a_cur, s_nxt = s_cur;
        if (r + 1 < R){
            a_nxt = ld4(Cp + (h0+r+1)*W4);
            s_nxt = ld4(Sp + (h0+r+1)*W4);
        }
        uint2 vmn = pmin2(rmn[r&3], pmin2(rmn[(r+1)&3], rmn[(r+2)&3]));
        uint2 vmx = pmax2(rmx[r&3], pmax2(rmx[(r+1)&3], rmx[(r+2)&3]));
        uint2 ew = hmin2(vmn, lane);
        *(Ep + (h0+r)*W4) = ew;
        uint2 ow = hmax2(vmx, lane);
        float4 o = cvt4(ow.x, ow.y);
        float4 a = a_cur;
        float4 s = s_cur;
        float4 up; float dl;
        dl = lk(a.x-o.x); up.x = lk(dl - s.x*dl)*lr; s.x += up.x;
        dl = lk(a.y-o.y); up.y = lk(dl - s.y*dl)*lr; s.y += up.y;
        dl = lk(a.z-o.z); up.z = lk(dl - s.z*dl)*lr; s.z += up.z;
        dl = lk(a.w-o.w); up.w = lk(dl - s.w*dl)*lr; s.w += up.w;
        st4(Sp + (h0+r)*W4, s);
        if constexpr(MODE == 2)
            loc += (double)(fabsf(s.x)+fabsf(s.y)+fabsf(s.z)+fabsf(s.w));
        else
            loc += (double)(fabsf(up.x)+fabsf(up.y)+fabsf(up.z)+fabsf(up.w));
        a_cur = a_nxt; s_cur = s_nxt;
    }
    return loc;
}

// Cooperative tail: iterations TSTART..19 + finalize. Common case (already
// frozen): read one flag and exit.
__global__ __launch_bounds__(256) void tail_k(h4* __restrict__ rg0,
                                              h4* __restrict__ rg1,
                                              h4* __restrict__ rg2,
                                              h4* __restrict__ S,
                                              float* __restrict__ outp,
                                              const double* __restrict__ pr0,
                                              double* __restrict__ tp0,
                                              double* __restrict__ tp1,
                                              const int* __restrict__ frozen){
    if (*frozen) return;                       // scale already done at freeze
    cooperative_groups::grid_group gg = cooperative_groups::this_grid();
    __shared__ double sm[4];
    int tid = threadIdx.x, lane = tid & 63, wv = tid >> 6;
    int bi = blockIdx.x;
    int d = bi >> 3, b = (bi >> 2) & 1, q = bi & 3;   // 1024 blocks, 16 rows/thread
    int h0 = q*64 + wv*16;
    size_t pbase = ((size_t)(b*128 + d))*PS + (size_t)lane;
    bool pm = d > 0, pp = d < 127;
    const double* pr = pr0; int prn = GBLK;
    double* tpw = tp0;
    for (int i = TSTART; i < 20; ++i){
        double v = 0.0;
        for (int j = 0; j < prn/256; ++j) v += pr[tid + 256*j];
#pragma unroll
        for (int o = 32; o; o >>= 1) v += __shfl_down(v, o);
        if (lane == 0) sm[wv] = v;
        __syncthreads();
        double tot = sm[0] + sm[1] + sm[2] + sm[3];
        if ((float)(tot / (double)NTOT) < STOPF) break;
        __syncthreads();
        int xs = (i+1)%3, es = (i+2)%3, cs = i%3;
        h4* X = xs==0 ? rg0 : (xs==1 ? rg1 : rg2);
        h4* E = es==0 ? rg0 : (es==1 ? rg1 : rg2);
        h4* C = cs==0 ? rg0 : (cs==1 ? rg1 : rg2);
        float lr = 0.1f * exp2f(-(float)(i >> 2));
        const uint2* Xc = (const uint2*)X + pbase;
        double loc = phase_pk<3,16>(Xc-PS, Xc, Xc+PS, pm, pp, (uint2*)E + pbase,
                                    C + pbase, S + pbase, lr, h0, lane);
#pragma unroll
        for (int o = 32; o; o >>= 1) loc += __shfl_down(loc, o);
        if (lane == 0) sm[wv] = loc;
        __syncthreads();
        if (tid == 0) tpw[blockIdx.x] = sm[0]+sm[1]+sm[2]+sm[3];
        gg.sync();
        pr = tpw; prn = 1024;
        tpw = (tpw == tp0) ? tp1 : tp0;
    }
    const h4* Sp = S + pbase;
    float4* O = (float4*)outp + pbase;
#pragma unroll
    for (int r = 0; r < 16; ++r){
        float4 s = h4tof4(Sp[(h0+r)*W4]);
        O[(h0+r)*W4] = make_float4(1.1f*s.x, 1.1f*s.y, 1.1f*s.z, 1.1f*s.w);
    }
}

// Fallback-only standalone scale (dt == 0 identically -> out = 1.1*S)
__global__ __launch_bounds__(256) void scale_k(const h4* __restrict__ S,
                                               float* __restrict__ out){
    int t = blockIdx.x*256 + threadIdx.x;
#pragma unroll
    for (int c = 0; c < 4; ++c){
        int i = t + c*1048576;
        float4 s = ld4(S + i);
        float4 r = make_float4(1.1f*s.x, 1.1f*s.y, 1.1f*s.z, 1.1f*s.w);
        *(float4*)(out + (size_t)i*4) = r;
    }
}

extern "C" void kernel_launch(void* const* d_in, const int* in_sizes, int n_in,
                              void* d_out, int out_size, void* d_ws, size_t ws_size,
                              hipStream_t stream){
    const float* img0 = (const float*)d_in[0];
    float* out = (float*)d_out;
    char* ws = (char*)d_ws;
    size_t volh = (size_t)NTOT * 2;            // fp16 volume: 33.5 MB
    h4* ring[3] = { (h4*)ws, (h4*)(ws + volh), (h4*)(ws + 2*volh) };
    h4* S       = (h4*)(ws + 3*volh);
    double* parts[2] = { (double*)(ws + 4*volh), (double*)(ws + 4*volh) + GBLK };
    int* frozen = (int*)(ws + 4*volh + 2*GBLK*sizeof(double));
    double* tp0 = (double*)(ws + 4*volh + 2*GBLK*sizeof(double) + 256);
    double* tp1 = tp0 + 1024;

    dim3 blk(256), grd(GBLK);
    // fused init: R0 = erode(img0); R1 = erode(R0); S = leaky(img0 - open(img0))
    hipLaunchKernelGGL(init_k, grd, blk, 0, stream, img0, ring[0], ring[1], S, frozen);

    // iterations 0..TSTART-1 as plain dispatches (kernel boundary = cheap barrier)
    for (int i = 0; i < TSTART; ++i){
        h4* C = ring[i % 3];
        h4* X = ring[(i+1) % 3];
        h4* E = ring[(i+2) % 3];
        float lr = (float)(0.1 * pow(0.5, (double)(i / 4)));
        double* pw = parts[i & 1];
        double* pr = parts[1 - (i & 1)];
        if (i == 0)
            hipLaunchKernelGGL((upd_k<2>), grd, blk, 0, stream, X, C, E, S, pr, pw, frozen, out, lr);
        else
            hipLaunchKernelGGL((upd_k<3>), grd, blk, 0, stream, X, C, E, S, pr, pw, frozen, out, lr);
    }

    // coop tail: iterations TSTART..19 + finalize (fast exit when frozen)
    h4* a_r0 = ring[0]; h4* a_r1 = ring[1]; h4* a_r2 = ring[2];
    h4* a_S = S; float* a_out = out;
    const double* a_pr0 = parts[1 - (TSTART & 1)];   // partials from i=TSTART-1
    double* a_tp0 = tp0; double* a_tp1 = tp1; int* a_fz = frozen;
    void* args[9] = { &a_r0, &a_r1, &a_r2, &a_S, &a_out, &a_pr0, &a_tp0, &a_tp1, &a_fz };
    hipError_t ce = hipLaunchCooperativeKernel((const void*)tail_k, dim3(1024), blk,
                                               args, 0u, stream);
    if (ce != hipSuccess){
        // fallback: plain dispatches for the remaining iterations
        for (int i = TSTART; i < 20; ++i){
            h4* C = ring[i % 3];
            h4* X = ring[(i+1) % 3];
            h4* E = ring[(i+2) % 3];
            float lr = (float)(0.1 * pow(0.5, (double)(i / 4)));
            double* pw = parts[i & 1];
            double* pr = parts[1 - (i & 1)];
            hipLaunchKernelGGL((upd_k<3>), grd, blk, 0, stream, X, C, E, S, pr, pw, frozen, out, lr);
        }
        hipLaunchKernelGGL(scale_k, dim3(4096), blk, 0, stream, S, out);
    }
}